// Round 8
// baseline (106.323 us; speedup 1.0000x reference)
//
#include <hip/hip_runtime.h>
#include <math.h>
#include <stdint.h>

#define NV 512
#define NF 1024
#define NGROUP 16
#define CHUNK 64

// ws layout:
//   keys : u64 [16384]   @ 0        (131072 B)
//   done : u32 [64]      @ 131072   (256 B)

// Fused everything: grid (64 tiles x 16 groups), 256 threads.
// Each block: camera matrix + 512 vertex transforms (LDS) + its 64 tris'
// affine coeffs (LDS) + bbox-compacted branch-free scan + atomicMin.
// Last block per tile colors the tile from LDS (done-counter epilogue).
__global__ __launch_bounds__(256, 4) void render_kernel(
    const float* __restrict__ v, const int* __restrict__ fidx,
    const float* __restrict__ camf, const float* __restrict__ camc,
    const float* __restrict__ camt, const float* __restrict__ camrt,
    const float* __restrict__ vc, const float* __restrict__ bg,
    unsigned long long* __restrict__ keys, unsigned int* __restrict__ done,
    float* __restrict__ out)
{
  __shared__ double sM[16];
  __shared__ double sxs[NV], sys_[NV], szn[NV], siw[NV];
  __shared__ int svld[NV];
  __shared__ double2 sc[5][CHUNK];    // raw coeffs (by local tri id)
  __shared__ double2 scc[5][CHUNK];   // bbox-compacted coeffs (dense)
  __shared__ float4 sbb[CHUNK];
  __shared__ int scidx[CHUNK];
  __shared__ int scnt;
  __shared__ int s_last;
  const int tid = threadIdx.x;
  const int tile = blockIdx.x;
  const int group = blockIdx.y;
  const int tbase = group * CHUNK;
  const int x0 = (tile & 7) << 4;
  const int y0 = (tile >> 3) << 4;

  {
#pragma clang fp contract(off)
    if (tid == 0) {
      // ---- Rodrigues: scalar part f32 (NEP50 weak promotion), matrices f64 ----
      float r0f = camrt[0], r1f = camrt[1], r2f = camrt[2];
      float th = sqrtf(((r0f * r0f + r1f * r1f) + r2f * r2f) + 1e-12f);
      float k0 = r0f / th, k1 = r1f / th, k2 = r2f / th;
      float sthf = sinf(th);
      float cthf = 1.0f - cosf(th);
      double K[3][3] = {{0.0, -(double)k2, (double)k1},
                        {(double)k2, 0.0, -(double)k0},
                        {-(double)k1, (double)k0, 0.0}};
      double KK[3][3];
      for (int i = 0; i < 3; ++i)
        for (int j = 0; j < 3; ++j)
          KK[i][j] = (K[i][0] * K[0][j] + K[i][1] * K[1][j]) + K[i][2] * K[2][j];
      double R[3][3];
      for (int i = 0; i < 3; ++i)
        for (int j = 0; j < 3; ++j) {
          double e = (i == j) ? 1.0 : 0.0;
          R[i][j] = (e + (double)sthf * K[i][j]) + (double)cthf * KK[i][j];
        }
      double Mr[4][4], Mt[4][4];
      for (int i = 0; i < 4; ++i)
        for (int j = 0; j < 4; ++j) {
          Mr[i][j] = (i == j) ? 1.0 : 0.0;
          Mt[i][j] = (i == j) ? 1.0 : 0.0;
        }
      for (int i = 0; i < 3; ++i)
        for (int j = 0; j < 3; ++j) Mr[i][j] = R[j][i];
      Mt[3][0] = (double)camt[0]; Mt[3][1] = (double)camt[1]; Mt[3][2] = (double)camt[2];
      double view[4][4];
      for (int i = 0; i < 4; ++i)
        for (int j = 0; j < 4; ++j)
          view[i][j] = ((Mr[i][0] * Mt[0][j] + Mr[i][1] * Mt[1][j]) +
                        Mr[i][2] * Mt[2][j]) + Mr[i][3] * Mt[3][j];
      float fcam = 0.5f * (camf[0] + camf[1]);
      float nf = 0.1f / fcam;
      float ccx = camc[0], ccy = camc[1];
      float right = (128.0f - (ccx + 0.5f)) * nf;
      float left = -(ccx + 0.5f) * nf;
      float top = (ccy + 0.5f) * nf;
      float bottom = -((128.0f - ccy) + 0.5f) * nf;
      float m00f = 0.2f / (right - left);
      float m02f = (right + left) / (right - left);
      float m11f = 0.2f / (top - bottom);
      float m12f = (top + bottom) / (top - bottom);
      double P[4][4] = {
          {(double)m00f, 0.0, (double)m02f, 0.0},
          {0.0, (double)m11f, (double)m12f, 0.0},
          {0.0, 0.0, -(10.0 + 0.1) / (10.0 - 0.1),
           -2.0 * 10.0 * 0.1 / (10.0 - 0.1)},
          {0.0, 0.0, -1.0, 0.0}};
      for (int i = 0; i < 4; ++i)
        for (int j = 0; j < 4; ++j)
          sM[i * 4 + j] = ((view[i][0] * P[j][0] + view[i][1] * P[j][1]) +
                           view[i][2] * P[j][2]) + view[i][3] * P[j][3];
    }
    __syncthreads();

    // ---- vertex transform, 2 per thread (expressions identical to r6/r7) ----
    for (int i = tid; i < NV; i += 256) {
      double x = (double)v[i * 3 + 0];
      double y = (double)v[i * 3 + 1];
      double zz = (double)v[i * 3 + 2];
      double c0 = ((x * sM[0] + y * sM[4]) + zz * sM[8]) + sM[12];
      double c1 = ((x * sM[1] + y * sM[5]) + zz * sM[9]) + sM[13];
      double c2 = ((x * sM[2] + y * sM[6]) + zz * sM[10]) + sM[14];
      double c3 = ((x * sM[3] + y * sM[7]) + zz * sM[11]) + sM[15];
      int valid = c3 > 1e-8;
      double wsafe = valid ? c3 : 1.0;
      double n0 = c0 / wsafe, n1 = c1 / wsafe, n2 = c2 / wsafe;
      double xs = (n0 * 0.5 + 0.5) * 128.0;
      double ys = (0.5 - n1 * 0.5) * 128.0;
      double iw = 1.0 / wsafe;
      sxs[i] = xs; sys_[i] = ys; szn[i] = n2; siw[i] = iw; svld[i] = valid;
    }
    __syncthreads();

    // ---- this block's 64 tris: affine coeffs + bbox into LDS ----
    if (tid < CHUNK) {
      const int t = tbase + tid;
      int i0 = fidx[t * 3 + 0], i1 = fidx[t * 3 + 1], i2 = fidx[t * 3 + 2];
      double ax = sxs[i0], ay = sys_[i0];
      double bx = sxs[i1], by = sys_[i1];
      double cx = sxs[i2], cy = sys_[i2];
      double p1 = (bx - ax) * (cy - ay);
      double p2 = (by - ay) * (cx - ax);
      double area = p1 - p2;
      bool ok = (fabs(area) > 1e-8) && svld[i0] && svld[i1] && svld[i2];
      double s = (area > 0.0) ? 1.0 : -1.0;
      double inv_abs = ok ? s / area : 1.0;   // 1/|area|, positive
      double kk0 = szn[i0] * inv_abs, kk1 = szn[i1] * inv_abs, kk2 = szn[i2] * inv_abs;

      // affine raster coeffs (r5/r6/r7-verified): w_i = A*px+B*py+C sign-folded;
      // w2 = |area| - w0 - w1; NaN area => never inside
      double e0x = cx - bx, e0y = cy - by;
      double e1x = ax - cx, e1y = ay - cy;
      double e2x = bx - ax, e2y = by - ay;
      double A0 = -s * e0y, B0 = s * e0x, C0 = s * (e0y * bx - e0x * by);
      double A1 = -s * e1y, B1 = s * e1x, C1 = s * (e1y * cx - e1x * cy);
      double A2 = -s * e2y, B2 = s * e2x, C2 = s * (e2y * ax - e2x * ay);
      double Az = (A0 * kk0 + A1 * kk1) + A2 * kk2;
      double Bz = (B0 * kk0 + B1 * kk1) + B2 * kk2;
      double Cz = (C0 * kk0 + C1 * kk1) + C2 * kk2;
      double absarea = ok ? (s * area) : __builtin_nan("");
      sc[0][tid] = make_double2(A0, B0);
      sc[1][tid] = make_double2(C0, A1);
      sc[2][tid] = make_double2(B1, C1);
      sc[3][tid] = make_double2(Az, Bz);
      sc[4][tid] = make_double2(Cz, absarea);
      float4 bb;
      if (ok) {
        bb.x = (float)(fmin(fmin(ax, bx), cx) - 0.01);
        bb.y = (float)(fmin(fmin(ay, by), cy) - 0.01);
        bb.z = (float)(fmax(fmax(ax, bx), cx) + 0.01);
        bb.w = (float)(fmax(fmax(ay, by), cy) + 0.01);
      } else {
        bb.x = 1e30f; bb.y = 1e30f; bb.z = -1e30f; bb.w = -1e30f;
      }
      sbb[tid] = bb;

      // bbox cull + RECORD compaction (same wave, in-order; addresses of the
      // scan's loads depend only on the induction var — no r5 indirection)
      const float txmin = (float)x0 + 0.5f, txmax = (float)x0 + 15.5f;
      const float tymin = (float)y0 + 0.5f, tymax = (float)y0 + 15.5f;
      bool hit = !(bb.x > txmax || bb.z < txmin || bb.y > tymax || bb.w < tymin);
      unsigned long long m = __ballot(hit);
      int pos = __popcll(m & ((1ull << tid) - 1ull));
      if (hit) {
        scc[0][pos] = sc[0][tid];
        scc[1][pos] = sc[1][tid];
        scc[2][pos] = sc[2][tid];
        scc[3][pos] = sc[3][tid];
        scc[4][pos] = sc[4][tid];
        scidx[pos] = tid;
      }
      if (tid == 0) scnt = (int)__popcll(m);
    }
  }
  __syncthreads();

  // ---- branch-free scan over compacted records (dense index j) ----
  const int x = x0 + (tid & 15);
  const int y = y0 + (tid >> 4);
  const double px = (double)x + 0.5, py = (double)y + 0.5;
  const int cnt = scnt;

  double bestz = INFINITY;
  int besti = -1;
#pragma unroll 4
  for (int j = 0; j < cnt; ++j) {
    double2 c0 = scc[0][j];   // A0 B0   (broadcast b128 reads)
    double2 c1 = scc[1][j];   // C0 A1
    double2 c2 = scc[2][j];   // B1 C1
    double2 c3 = scc[3][j];   // Az Bz
    double2 c4 = scc[4][j];   // Cz |area|
    int torig = scidx[j];     // leaf load, feeds only the select
    double w0 = (c0.x * px + c0.y * py) + c1.x;
    double w1 = (c1.y * px + c2.x * py) + c2.y;
    double z  = (c3.x * px + c3.y * py) + c4.x;
    double w2 = (c4.y - w0) - w1;
    bool ins = (w0 >= 0.0) & (w1 >= 0.0) & (w2 >= 0.0) &
               (z >= -1.0) & (z <= 1.0) & (z < bestz);
    bestz = ins ? z : bestz;
    besti = ins ? (tbase + torig) : besti;
  }
  if (besti >= 0) {
    unsigned long long zq = (unsigned long long)((bestz + 1.0) * 4503599627370496.0);
    atomicMin(&keys[y * 128 + x], (zq << 10) | (unsigned long long)besti);
  }

  // ---- done-counter epilogue: last block per tile colors the tile ----
  __syncthreads();
  if (tid == 0) {
    __threadfence();
    unsigned int old = __hip_atomic_fetch_add(&done[tile], 1u, __ATOMIC_ACQ_REL,
                                              __HIP_MEMORY_SCOPE_AGENT);
    s_last = (old == NGROUP - 1) ? 1 : 0;
  }
  __syncthreads();

  if (s_last) {
    const int p = y * 128 + x;
    unsigned long long key = __hip_atomic_load(&keys[p], __ATOMIC_RELAXED,
                                               __HIP_MEMORY_SCOPE_AGENT);
    float cr, cg, cb;
    if (key == ~0ull) {
      cr = bg[0]; cg = bg[1]; cb = bg[2];
    } else {
#pragma clang fp contract(off)
      // recompute winner color from LDS verts — expressions verbatim from the
      // verified setup(tridata)+color pipeline
      unsigned int t = (unsigned int)(key & 1023ull);
      int i0 = fidx[t * 3 + 0], i1 = fidx[t * 3 + 1], i2 = fidx[t * 3 + 2];
      double ax = sxs[i0], ay = sys_[i0];
      double bx = sxs[i1], by = sys_[i1];
      double cx = sxs[i2], cy = sys_[i2];
      double p1 = (bx - ax) * (cy - ay);
      double p2 = (by - ay) * (cx - ax);
      double area = p1 - p2;
      bool ok = (fabs(area) > 1e-8) && svld[i0] && svld[i1] && svld[i2];
      double s = (area > 0.0) ? 1.0 : -1.0;
      double inv = ok ? s / area : 1.0;
      double d6 = s * (cx - bx), d7 = s * (cy - by);
      double d8 = s * (ax - cx), d9 = s * (ay - cy);
      double d10 = s * (bx - ax), d11 = s * (by - ay);
      double w0 = d6 * (py - by) - d7 * (px - bx);
      double w1 = d8 * (py - cy) - d9 * (px - cx);
      double w2 = d10 * (py - ay) - d11 * (px - ax);
      double b0 = w0 * inv, b1 = w1 * inv, b2 = w2 * inv;
      double t0 = b0 * siw[i0];
      double t1 = b1 * siw[i1];
      double t2 = b2 * siw[i2];
      double den = (t0 + t1) + t2;
      if (!(fabs(den) > 1e-8)) den = 1.0;
      cr = (float)((((t0 * (double)vc[i0 * 3 + 0] + t1 * (double)vc[i1 * 3 + 0]) +
                     t2 * (double)vc[i2 * 3 + 0])) / den);
      cg = (float)((((t0 * (double)vc[i0 * 3 + 1] + t1 * (double)vc[i1 * 3 + 1]) +
                     t2 * (double)vc[i2 * 3 + 1])) / den);
      cb = (float)((((t0 * (double)vc[i0 * 3 + 2] + t1 * (double)vc[i1 * 3 + 2]) +
                     t2 * (double)vc[i2 * 3 + 2])) / den);
    }
    out[p * 3 + 0] = cr;
    out[p * 3 + 1] = cg;
    out[p * 3 + 2] = cb;
  }
}

extern "C" void kernel_launch(void* const* d_in, const int* in_sizes, int n_in,
                              void* d_out, int out_size, void* d_ws, size_t ws_size,
                              hipStream_t stream) {
  const float* v = (const float*)d_in[0];
  const float* vc = (const float*)d_in[1];
  const int* fidx = (const int*)d_in[2];
  const float* bg = (const float*)d_in[3];
  const float* camf = (const float*)d_in[4];
  const float* camc = (const float*)d_in[5];
  const float* camt = (const float*)d_in[6];
  const float* camrt = (const float*)d_in[7];
  float* out = (float*)d_out;

  char* ws = (char*)d_ws;
  unsigned long long* keys = (unsigned long long*)ws;        // @0
  unsigned int* done = (unsigned int*)(ws + 131072);         // 64 u32

  hipMemsetAsync(keys, 0xFF, 16384 * sizeof(unsigned long long), stream);
  hipMemsetAsync(done, 0x00, 64 * sizeof(unsigned int), stream);
  render_kernel<<<dim3(64, NGROUP), 256, 0, stream>>>(
      v, fidx, camf, camc, camt, camrt, vc, bg, keys, done, out);
}

// Round 9
// 87.842 us; speedup vs baseline: 1.2104x; 1.2104x over previous
//
#include <hip/hip_runtime.h>
#include <math.h>
#include <stdint.h>

#define NV 512
#define NF 1024
#define TRI_STRIDE 16
#define NGROUP 16
#define CHUNK 64

// ws layout (16B-aligned blocks):
//   keys   : u64 [16384]        @ 0        (131072 B)
//   vdata  : f64 [4][512]       @ 131072   (16384 B)   xs, ys, z_ndc, inv_w
//   tridata: f64 [1024*16]      @ 147456   (131072 B)  exact ref-order data (color)
// total 278528 B

// r7 champion structure + register-direct bbox compaction.
// NO per-block fences / done counters (r8 counter evidence: agent-scope
// release per block => L2 writeback storm, WRITE_SIZE 13x keys, VALU 9.5%).
__global__ __launch_bounds__(256, 4) void render_kernel(
    const float* __restrict__ v, const int* __restrict__ fidx,
    const float* __restrict__ camf, const float* __restrict__ camc,
    const float* __restrict__ camt, const float* __restrict__ camrt,
    double* __restrict__ vdata, double* __restrict__ tridata,
    unsigned long long* __restrict__ keys)
{
  __shared__ double sM[16];
  __shared__ double sxs[NV], sys_[NV], szn[NV];
  __shared__ int svld[NV];
  __shared__ double2 scc[5][CHUNK];   // bbox-compacted coeffs (dense)
  __shared__ int scidx[CHUNK];
  __shared__ int scnt;
  const int tid = threadIdx.x;
  const int tile = blockIdx.x;
  const int group = blockIdx.y;
  const int tbase = group * CHUNK;
  const int x0 = (tile & 7) << 4;
  const int y0 = (tile >> 3) << 4;

  {
#pragma clang fp contract(off)
    if (tid == 0) {
      // ---- Rodrigues: scalar part f32 (NEP50 weak promotion), matrices f64 ----
      float r0f = camrt[0], r1f = camrt[1], r2f = camrt[2];
      float th = sqrtf(((r0f * r0f + r1f * r1f) + r2f * r2f) + 1e-12f);
      float k0 = r0f / th, k1 = r1f / th, k2 = r2f / th;
      float sthf = sinf(th);
      float cthf = 1.0f - cosf(th);
      double K[3][3] = {{0.0, -(double)k2, (double)k1},
                        {(double)k2, 0.0, -(double)k0},
                        {-(double)k1, (double)k0, 0.0}};
      double KK[3][3];
      for (int i = 0; i < 3; ++i)
        for (int j = 0; j < 3; ++j)
          KK[i][j] = (K[i][0] * K[0][j] + K[i][1] * K[1][j]) + K[i][2] * K[2][j];
      double R[3][3];
      for (int i = 0; i < 3; ++i)
        for (int j = 0; j < 3; ++j) {
          double e = (i == j) ? 1.0 : 0.0;
          R[i][j] = (e + (double)sthf * K[i][j]) + (double)cthf * KK[i][j];
        }
      double Mr[4][4], Mt[4][4];
      for (int i = 0; i < 4; ++i)
        for (int j = 0; j < 4; ++j) {
          Mr[i][j] = (i == j) ? 1.0 : 0.0;
          Mt[i][j] = (i == j) ? 1.0 : 0.0;
        }
      for (int i = 0; i < 3; ++i)
        for (int j = 0; j < 3; ++j) Mr[i][j] = R[j][i];
      Mt[3][0] = (double)camt[0]; Mt[3][1] = (double)camt[1]; Mt[3][2] = (double)camt[2];
      double view[4][4];
      for (int i = 0; i < 4; ++i)
        for (int j = 0; j < 4; ++j)
          view[i][j] = ((Mr[i][0] * Mt[0][j] + Mr[i][1] * Mt[1][j]) +
                        Mr[i][2] * Mt[2][j]) + Mr[i][3] * Mt[3][j];
      float fcam = 0.5f * (camf[0] + camf[1]);
      float nf = 0.1f / fcam;
      float ccx = camc[0], ccy = camc[1];
      float right = (128.0f - (ccx + 0.5f)) * nf;
      float left = -(ccx + 0.5f) * nf;
      float top = (ccy + 0.5f) * nf;
      float bottom = -((128.0f - ccy) + 0.5f) * nf;
      float m00f = 0.2f / (right - left);
      float m02f = (right + left) / (right - left);
      float m11f = 0.2f / (top - bottom);
      float m12f = (top + bottom) / (top - bottom);
      double P[4][4] = {
          {(double)m00f, 0.0, (double)m02f, 0.0},
          {0.0, (double)m11f, (double)m12f, 0.0},
          {0.0, 0.0, -(10.0 + 0.1) / (10.0 - 0.1),
           -2.0 * 10.0 * 0.1 / (10.0 - 0.1)},
          {0.0, 0.0, -1.0, 0.0}};
      for (int i = 0; i < 4; ++i)
        for (int j = 0; j < 4; ++j)
          sM[i * 4 + j] = ((view[i][0] * P[j][0] + view[i][1] * P[j][1]) +
                           view[i][2] * P[j][2]) + view[i][3] * P[j][3];
    }
    __syncthreads();

    // ---- vertex transform, 2 per thread (expressions identical to r6/r7) ----
    for (int i = tid; i < NV; i += 256) {
      double x = (double)v[i * 3 + 0];
      double y = (double)v[i * 3 + 1];
      double zz = (double)v[i * 3 + 2];
      double c0 = ((x * sM[0] + y * sM[4]) + zz * sM[8]) + sM[12];
      double c1 = ((x * sM[1] + y * sM[5]) + zz * sM[9]) + sM[13];
      double c2 = ((x * sM[2] + y * sM[6]) + zz * sM[10]) + sM[14];
      double c3 = ((x * sM[3] + y * sM[7]) + zz * sM[11]) + sM[15];
      int valid = c3 > 1e-8;
      double wsafe = valid ? c3 : 1.0;
      double n0 = c0 / wsafe, n1 = c1 / wsafe, n2 = c2 / wsafe;
      double xs = (n0 * 0.5 + 0.5) * 128.0;
      double ys = (0.5 - n1 * 0.5) * 128.0;
      double iw = 1.0 / wsafe;
      sxs[i] = xs; sys_[i] = ys; szn[i] = n2; svld[i] = valid;
      if (tile == 0 && group == 0) {
        vdata[0 * NV + i] = xs;
        vdata[1 * NV + i] = ys;
        vdata[2 * NV + i] = n2;
        vdata[3 * NV + i] = iw;
      }
    }
    __syncthreads();

    // ---- this block's 64 tris: coeffs in registers, bbox cull, scatter
    //      straight into compacted LDS (no raw array, no LDS->LDS copy) ----
    if (tid < CHUNK) {
      const int t = tbase + tid;
      int i0 = fidx[t * 3 + 0], i1 = fidx[t * 3 + 1], i2 = fidx[t * 3 + 2];
      double ax = sxs[i0], ay = sys_[i0];
      double bx = sxs[i1], by = sys_[i1];
      double cx = sxs[i2], cy = sys_[i2];
      double p1 = (bx - ax) * (cy - ay);
      double p2 = (by - ay) * (cx - ax);
      double area = p1 - p2;
      bool ok = (fabs(area) > 1e-8) && svld[i0] && svld[i1] && svld[i2];
      double s = (area > 0.0) ? 1.0 : -1.0;
      double inv_abs = ok ? s / area : 1.0;   // 1/|area|, positive
      double kk0 = szn[i0] * inv_abs, kk1 = szn[i1] * inv_abs, kk2 = szn[i2] * inv_abs;

      if (tile == 0) {
        // exact-path record for the color pass (verified round-2 layout)
        double* td = tridata + t * TRI_STRIDE;
        td[0] = bx;  td[1] = by;  td[2] = cx;  td[3] = cy;  td[4] = ax;  td[5] = ay;
        td[6] = s * (cx - bx);  td[7] = s * (cy - by);
        td[8] = s * (ax - cx);  td[9] = s * (ay - cy);
        td[10] = s * (bx - ax); td[11] = s * (by - ay);
        td[12] = kk0; td[13] = kk1; td[14] = kk2;
        td[15] = inv_abs;
      }

      // affine raster coeffs (r5/r6/r7-verified): w_i = A*px+B*py+C sign-folded;
      // w2 = |area| - w0 - w1; NaN area => never inside
      double e0x = cx - bx, e0y = cy - by;
      double e1x = ax - cx, e1y = ay - cy;
      double e2x = bx - ax, e2y = by - ay;
      double A0 = -s * e0y, B0 = s * e0x, C0 = s * (e0y * bx - e0x * by);
      double A1 = -s * e1y, B1 = s * e1x, C1 = s * (e1y * cx - e1x * cy);
      double A2 = -s * e2y, B2 = s * e2x, C2 = s * (e2y * ax - e2x * ay);
      double Az = (A0 * kk0 + A1 * kk1) + A2 * kk2;
      double Bz = (B0 * kk0 + B1 * kk1) + B2 * kk2;
      double Cz = (C0 * kk0 + C1 * kk1) + C2 * kk2;
      double absarea = ok ? (s * area) : __builtin_nan("");

      // bbox tile cull + compacted scatter (wave 0, in-order)
      float bminx, bminy, bmaxx, bmaxy;
      if (ok) {
        bminx = (float)(fmin(fmin(ax, bx), cx) - 0.01);
        bminy = (float)(fmin(fmin(ay, by), cy) - 0.01);
        bmaxx = (float)(fmax(fmax(ax, bx), cx) + 0.01);
        bmaxy = (float)(fmax(fmax(ay, by), cy) + 0.01);
      } else {
        bminx = 1e30f; bminy = 1e30f; bmaxx = -1e30f; bmaxy = -1e30f;
      }
      const float txmin = (float)x0 + 0.5f, txmax = (float)x0 + 15.5f;
      const float tymin = (float)y0 + 0.5f, tymax = (float)y0 + 15.5f;
      bool hit = !(bminx > txmax || bmaxx < txmin || bminy > tymax || bmaxy < tymin);
      unsigned long long m = __ballot(hit);
      int pos = __popcll(m & ((1ull << tid) - 1ull));
      if (hit) {
        scc[0][pos] = make_double2(A0, B0);
        scc[1][pos] = make_double2(C0, A1);
        scc[2][pos] = make_double2(B1, C1);
        scc[3][pos] = make_double2(Az, Bz);
        scc[4][pos] = make_double2(Cz, absarea);
        scidx[pos] = tid;
      }
      if (tid == 0) scnt = (int)__popcll(m);
    }
  }
  __syncthreads();

  // ---- branch-free scan over compacted records (dense index j) ----
  const int x = x0 + (tid & 15);
  const int y = y0 + (tid >> 4);
  const double px = (double)x + 0.5, py = (double)y + 0.5;
  const int cnt = scnt;

  double bestz = INFINITY;
  int besti = -1;
#pragma unroll 4
  for (int j = 0; j < cnt; ++j) {
    double2 c0 = scc[0][j];   // A0 B0   (broadcast b128 reads)
    double2 c1 = scc[1][j];   // C0 A1
    double2 c2 = scc[2][j];   // B1 C1
    double2 c3 = scc[3][j];   // Az Bz
    double2 c4 = scc[4][j];   // Cz |area|
    int torig = scidx[j];     // leaf load, feeds only the select
    double w0 = (c0.x * px + c0.y * py) + c1.x;
    double w1 = (c1.y * px + c2.x * py) + c2.y;
    double z  = (c3.x * px + c3.y * py) + c4.x;
    double w2 = (c4.y - w0) - w1;
    bool ins = (w0 >= 0.0) & (w1 >= 0.0) & (w2 >= 0.0) &
               (z >= -1.0) & (z <= 1.0) & (z < bestz);
    bestz = ins ? z : bestz;
    besti = ins ? (tbase + torig) : besti;
  }
  if (besti >= 0) {
    unsigned long long zq = (unsigned long long)((bestz + 1.0) * 4503599627370496.0);
    atomicMin(&keys[y * 128 + x], (zq << 10) | (unsigned long long)besti);
  }
}

__global__ __launch_bounds__(256) void color_kernel(
    const unsigned long long* __restrict__ keys,
    const double* __restrict__ vdata, const double* __restrict__ tridata,
    const int* __restrict__ fidx, const float* __restrict__ vc,
    const float* __restrict__ bg, float* __restrict__ out)
{
  const int p = blockIdx.x * 256 + threadIdx.x;
  if (p >= 16384) return;
  const int x = p & 127, y = p >> 7;
  unsigned long long key = keys[p];
  float cr, cg, cb;
  if (key == ~0ull) {
    cr = bg[0]; cg = bg[1]; cb = bg[2];
  } else {
    unsigned int t = (unsigned int)(key & 1023ull);
    const double* td = tridata + t * TRI_STRIDE;
    double px = (double)x + 0.5, py = (double)y + 0.5;
    double w0 = td[6] * (py - td[1]) - td[7] * (px - td[0]);
    double w1 = td[8] * (py - td[3]) - td[9] * (px - td[2]);
    double w2 = td[10] * (py - td[5]) - td[11] * (px - td[4]);
    double inv = td[15];
    double b0 = w0 * inv, b1 = w1 * inv, b2 = w2 * inv;
    int i0 = fidx[t * 3 + 0], i1 = fidx[t * 3 + 1], i2 = fidx[t * 3 + 2];
    double t0 = b0 * vdata[3 * NV + i0];
    double t1 = b1 * vdata[3 * NV + i1];
    double t2 = b2 * vdata[3 * NV + i2];
    double den = (t0 + t1) + t2;
    if (!(fabs(den) > 1e-8)) den = 1.0;
    cr = (float)((((t0 * (double)vc[i0 * 3 + 0] + t1 * (double)vc[i1 * 3 + 0]) +
                   t2 * (double)vc[i2 * 3 + 0])) / den);
    cg = (float)((((t0 * (double)vc[i0 * 3 + 1] + t1 * (double)vc[i1 * 3 + 1]) +
                   t2 * (double)vc[i2 * 3 + 1])) / den);
    cb = (float)((((t0 * (double)vc[i0 * 3 + 2] + t1 * (double)vc[i1 * 3 + 2]) +
                   t2 * (double)vc[i2 * 3 + 2])) / den);
  }
  out[p * 3 + 0] = cr;
  out[p * 3 + 1] = cg;
  out[p * 3 + 2] = cb;
}

extern "C" void kernel_launch(void* const* d_in, const int* in_sizes, int n_in,
                              void* d_out, int out_size, void* d_ws, size_t ws_size,
                              hipStream_t stream) {
  const float* v = (const float*)d_in[0];
  const float* vc = (const float*)d_in[1];
  const int* fidx = (const int*)d_in[2];
  const float* bg = (const float*)d_in[3];
  const float* camf = (const float*)d_in[4];
  const float* camc = (const float*)d_in[5];
  const float* camt = (const float*)d_in[6];
  const float* camrt = (const float*)d_in[7];
  float* out = (float*)d_out;

  char* ws = (char*)d_ws;
  unsigned long long* keys = (unsigned long long*)ws;   // @0
  double* vdata = (double*)(ws + 131072);
  double* tridata = (double*)(ws + 147456);

  hipMemsetAsync(keys, 0xFF, 16384 * sizeof(unsigned long long), stream);
  render_kernel<<<dim3(64, NGROUP), 256, 0, stream>>>(
      v, fidx, camf, camc, camt, camrt, vdata, tridata, keys);
  color_kernel<<<64, 256, 0, stream>>>(keys, vdata, tridata, fidx, vc, bg, out);
}

// Round 10
// 86.433 us; speedup vs baseline: 1.2301x; 1.0163x over previous
//
#include <hip/hip_runtime.h>
#include <math.h>
#include <stdint.h>

#define NV 512
#define NF 1024
#define TRI_STRIDE 16
#define NGROUP 16
#define CHUNK 64

// ws layout (16B-aligned blocks):
//   keys   : u64 [16384]        @ 0        (131072 B)
//   vdata  : f64 [4][512]       @ 131072   (16384 B)   xs, ys, z_ndc, inv_w
//   tridata: f64 [1024*16]      @ 147456   (131072 B)  exact ref-order data (color)
// total 278528 B

// r9 champion + 32x16 tiles with 2 px/thread: halves per-CU LDS scan traffic
// and halves redundant vertex setup (512 blocks). Two independent pixel
// chains per thread restore ILP lost to the lower wave count.
// NO per-block fences (r8: agent-scope release per block => L2 writeback storm).
__global__ __launch_bounds__(256, 4) void render_kernel(
    const float* __restrict__ v, const int* __restrict__ fidx,
    const float* __restrict__ camf, const float* __restrict__ camc,
    const float* __restrict__ camt, const float* __restrict__ camrt,
    double* __restrict__ vdata, double* __restrict__ tridata,
    unsigned long long* __restrict__ keys)
{
  __shared__ double sM[16];
  __shared__ double sxs[NV], sys_[NV], szn[NV];
  __shared__ int svld[NV];
  __shared__ double2 scc[5][CHUNK];   // bbox-compacted coeffs (dense)
  __shared__ int scidx[CHUNK];
  __shared__ int scnt;
  const int tid = threadIdx.x;
  const int tile = blockIdx.x;        // 32 tiles of 32x16
  const int group = blockIdx.y;
  const int tbase = group * CHUNK;
  const int x0 = (tile & 3) << 5;
  const int y0 = (tile >> 2) << 4;

  {
#pragma clang fp contract(off)
    if (tid == 0) {
      // ---- Rodrigues: scalar part f32 (NEP50 weak promotion), matrices f64 ----
      float r0f = camrt[0], r1f = camrt[1], r2f = camrt[2];
      float th = sqrtf(((r0f * r0f + r1f * r1f) + r2f * r2f) + 1e-12f);
      float k0 = r0f / th, k1 = r1f / th, k2 = r2f / th;
      float sthf = sinf(th);
      float cthf = 1.0f - cosf(th);
      double K[3][3] = {{0.0, -(double)k2, (double)k1},
                        {(double)k2, 0.0, -(double)k0},
                        {-(double)k1, (double)k0, 0.0}};
      double KK[3][3];
      for (int i = 0; i < 3; ++i)
        for (int j = 0; j < 3; ++j)
          KK[i][j] = (K[i][0] * K[0][j] + K[i][1] * K[1][j]) + K[i][2] * K[2][j];
      double R[3][3];
      for (int i = 0; i < 3; ++i)
        for (int j = 0; j < 3; ++j) {
          double e = (i == j) ? 1.0 : 0.0;
          R[i][j] = (e + (double)sthf * K[i][j]) + (double)cthf * KK[i][j];
        }
      double Mr[4][4], Mt[4][4];
      for (int i = 0; i < 4; ++i)
        for (int j = 0; j < 4; ++j) {
          Mr[i][j] = (i == j) ? 1.0 : 0.0;
          Mt[i][j] = (i == j) ? 1.0 : 0.0;
        }
      for (int i = 0; i < 3; ++i)
        for (int j = 0; j < 3; ++j) Mr[i][j] = R[j][i];
      Mt[3][0] = (double)camt[0]; Mt[3][1] = (double)camt[1]; Mt[3][2] = (double)camt[2];
      double view[4][4];
      for (int i = 0; i < 4; ++i)
        for (int j = 0; j < 4; ++j)
          view[i][j] = ((Mr[i][0] * Mt[0][j] + Mr[i][1] * Mt[1][j]) +
                        Mr[i][2] * Mt[2][j]) + Mr[i][3] * Mt[3][j];
      float fcam = 0.5f * (camf[0] + camf[1]);
      float nf = 0.1f / fcam;
      float ccx = camc[0], ccy = camc[1];
      float right = (128.0f - (ccx + 0.5f)) * nf;
      float left = -(ccx + 0.5f) * nf;
      float top = (ccy + 0.5f) * nf;
      float bottom = -((128.0f - ccy) + 0.5f) * nf;
      float m00f = 0.2f / (right - left);
      float m02f = (right + left) / (right - left);
      float m11f = 0.2f / (top - bottom);
      float m12f = (top + bottom) / (top - bottom);
      double P[4][4] = {
          {(double)m00f, 0.0, (double)m02f, 0.0},
          {0.0, (double)m11f, (double)m12f, 0.0},
          {0.0, 0.0, -(10.0 + 0.1) / (10.0 - 0.1),
           -2.0 * 10.0 * 0.1 / (10.0 - 0.1)},
          {0.0, 0.0, -1.0, 0.0}};
      for (int i = 0; i < 4; ++i)
        for (int j = 0; j < 4; ++j)
          sM[i * 4 + j] = ((view[i][0] * P[j][0] + view[i][1] * P[j][1]) +
                           view[i][2] * P[j][2]) + view[i][3] * P[j][3];
    }
    __syncthreads();

    // ---- vertex transform, 2 per thread (expressions identical to r6-r9) ----
    for (int i = tid; i < NV; i += 256) {
      double x = (double)v[i * 3 + 0];
      double y = (double)v[i * 3 + 1];
      double zz = (double)v[i * 3 + 2];
      double c0 = ((x * sM[0] + y * sM[4]) + zz * sM[8]) + sM[12];
      double c1 = ((x * sM[1] + y * sM[5]) + zz * sM[9]) + sM[13];
      double c2 = ((x * sM[2] + y * sM[6]) + zz * sM[10]) + sM[14];
      double c3 = ((x * sM[3] + y * sM[7]) + zz * sM[11]) + sM[15];
      int valid = c3 > 1e-8;
      double wsafe = valid ? c3 : 1.0;
      double n0 = c0 / wsafe, n1 = c1 / wsafe, n2 = c2 / wsafe;
      double xs = (n0 * 0.5 + 0.5) * 128.0;
      double ys = (0.5 - n1 * 0.5) * 128.0;
      double iw = 1.0 / wsafe;
      sxs[i] = xs; sys_[i] = ys; szn[i] = n2; svld[i] = valid;
      if (tile == 0 && group == 0) {
        vdata[0 * NV + i] = xs;
        vdata[1 * NV + i] = ys;
        vdata[2 * NV + i] = n2;
        vdata[3 * NV + i] = iw;
      }
    }
    __syncthreads();

    // ---- this block's 64 tris: coeffs in registers, bbox cull, scatter
    //      straight into compacted LDS ----
    if (tid < CHUNK) {
      const int t = tbase + tid;
      int i0 = fidx[t * 3 + 0], i1 = fidx[t * 3 + 1], i2 = fidx[t * 3 + 2];
      double ax = sxs[i0], ay = sys_[i0];
      double bx = sxs[i1], by = sys_[i1];
      double cx = sxs[i2], cy = sys_[i2];
      double p1 = (bx - ax) * (cy - ay);
      double p2 = (by - ay) * (cx - ax);
      double area = p1 - p2;
      bool ok = (fabs(area) > 1e-8) && svld[i0] && svld[i1] && svld[i2];
      double s = (area > 0.0) ? 1.0 : -1.0;
      double inv_abs = ok ? s / area : 1.0;   // 1/|area|, positive
      double kk0 = szn[i0] * inv_abs, kk1 = szn[i1] * inv_abs, kk2 = szn[i2] * inv_abs;

      if (tile == 0) {
        // exact-path record for the color pass (verified round-2 layout)
        double* td = tridata + t * TRI_STRIDE;
        td[0] = bx;  td[1] = by;  td[2] = cx;  td[3] = cy;  td[4] = ax;  td[5] = ay;
        td[6] = s * (cx - bx);  td[7] = s * (cy - by);
        td[8] = s * (ax - cx);  td[9] = s * (ay - cy);
        td[10] = s * (bx - ax); td[11] = s * (by - ay);
        td[12] = kk0; td[13] = kk1; td[14] = kk2;
        td[15] = inv_abs;
      }

      // affine raster coeffs (r5-r9 verified): w_i = A*px+B*py+C sign-folded;
      // w2 = |area| - w0 - w1; NaN area => never inside
      double e0x = cx - bx, e0y = cy - by;
      double e1x = ax - cx, e1y = ay - cy;
      double e2x = bx - ax, e2y = by - ay;
      double A0 = -s * e0y, B0 = s * e0x, C0 = s * (e0y * bx - e0x * by);
      double A1 = -s * e1y, B1 = s * e1x, C1 = s * (e1y * cx - e1x * cy);
      double A2 = -s * e2y, B2 = s * e2x, C2 = s * (e2y * ax - e2x * ay);
      double Az = (A0 * kk0 + A1 * kk1) + A2 * kk2;
      double Bz = (B0 * kk0 + B1 * kk1) + B2 * kk2;
      double Cz = (C0 * kk0 + C1 * kk1) + C2 * kk2;
      double absarea = ok ? (s * area) : __builtin_nan("");

      float bminx, bminy, bmaxx, bmaxy;
      if (ok) {
        bminx = (float)(fmin(fmin(ax, bx), cx) - 0.01);
        bminy = (float)(fmin(fmin(ay, by), cy) - 0.01);
        bmaxx = (float)(fmax(fmax(ax, bx), cx) + 0.01);
        bmaxy = (float)(fmax(fmax(ay, by), cy) + 0.01);
      } else {
        bminx = 1e30f; bminy = 1e30f; bmaxx = -1e30f; bmaxy = -1e30f;
      }
      const float txmin = (float)x0 + 0.5f, txmax = (float)x0 + 31.5f;
      const float tymin = (float)y0 + 0.5f, tymax = (float)y0 + 15.5f;
      bool hit = !(bminx > txmax || bmaxx < txmin || bminy > tymax || bmaxy < tymin);
      unsigned long long m = __ballot(hit);
      int pos = __popcll(m & ((1ull << tid) - 1ull));
      if (hit) {
        scc[0][pos] = make_double2(A0, B0);
        scc[1][pos] = make_double2(C0, A1);
        scc[2][pos] = make_double2(B1, C1);
        scc[3][pos] = make_double2(Az, Bz);
        scc[4][pos] = make_double2(Cz, absarea);
        scidx[pos] = tid;
      }
      if (tid == 0) scnt = (int)__popcll(m);
    }
  }
  __syncthreads();

  // ---- branch-free scan, 2 pixels per thread (x and x+16, same row) ----
  const int xa = x0 + (tid & 15);
  const int y = y0 + (tid >> 4);
  const double pxa = (double)xa + 0.5, pxb = (double)(xa + 16) + 0.5;
  const double py = (double)y + 0.5;
  const int cnt = scnt;

  double bestza = INFINITY, bestzb = INFINITY;
  int bestia = -1, bestib = -1;
#pragma unroll 4
  for (int j = 0; j < cnt; ++j) {
    double2 c0 = scc[0][j];   // A0 B0   (broadcast b128 reads)
    double2 c1 = scc[1][j];   // C0 A1
    double2 c2 = scc[2][j];   // B1 C1
    double2 c3 = scc[3][j];   // Az Bz
    double2 c4 = scc[4][j];   // Cz |area|
    int torig = scidx[j];     // leaf load, feeds only the selects
    // pixel A
    double w0a = (c0.x * pxa + c0.y * py) + c1.x;
    double w1a = (c1.y * pxa + c2.x * py) + c2.y;
    double za  = (c3.x * pxa + c3.y * py) + c4.x;
    double w2a = (c4.y - w0a) - w1a;
    bool insa = (w0a >= 0.0) & (w1a >= 0.0) & (w2a >= 0.0) &
                (za >= -1.0) & (za <= 1.0) & (za < bestza);
    bestza = insa ? za : bestza;
    bestia = insa ? (tbase + torig) : bestia;
    // pixel B (independent chain)
    double w0b = (c0.x * pxb + c0.y * py) + c1.x;
    double w1b = (c1.y * pxb + c2.x * py) + c2.y;
    double zb  = (c3.x * pxb + c3.y * py) + c4.x;
    double w2b = (c4.y - w0b) - w1b;
    bool insb = (w0b >= 0.0) & (w1b >= 0.0) & (w2b >= 0.0) &
                (zb >= -1.0) & (zb <= 1.0) & (zb < bestzb);
    bestzb = insb ? zb : bestzb;
    bestib = insb ? (tbase + torig) : bestib;
  }
  if (bestia >= 0) {
    unsigned long long zq = (unsigned long long)((bestza + 1.0) * 4503599627370496.0);
    atomicMin(&keys[y * 128 + xa], (zq << 10) | (unsigned long long)bestia);
  }
  if (bestib >= 0) {
    unsigned long long zq = (unsigned long long)((bestzb + 1.0) * 4503599627370496.0);
    atomicMin(&keys[y * 128 + xa + 16], (zq << 10) | (unsigned long long)bestib);
  }
}

__global__ __launch_bounds__(256) void color_kernel(
    const unsigned long long* __restrict__ keys,
    const double* __restrict__ vdata, const double* __restrict__ tridata,
    const int* __restrict__ fidx, const float* __restrict__ vc,
    const float* __restrict__ bg, float* __restrict__ out)
{
  const int p = blockIdx.x * 256 + threadIdx.x;
  if (p >= 16384) return;
  const int x = p & 127, y = p >> 7;
  unsigned long long key = keys[p];
  float cr, cg, cb;
  if (key == ~0ull) {
    cr = bg[0]; cg = bg[1]; cb = bg[2];
  } else {
    unsigned int t = (unsigned int)(key & 1023ull);
    const double* td = tridata + t * TRI_STRIDE;
    double px = (double)x + 0.5, py = (double)y + 0.5;
    double w0 = td[6] * (py - td[1]) - td[7] * (px - td[0]);
    double w1 = td[8] * (py - td[3]) - td[9] * (px - td[2]);
    double w2 = td[10] * (py - td[5]) - td[11] * (px - td[4]);
    double inv = td[15];
    double b0 = w0 * inv, b1 = w1 * inv, b2 = w2 * inv;
    int i0 = fidx[t * 3 + 0], i1 = fidx[t * 3 + 1], i2 = fidx[t * 3 + 2];
    double t0 = b0 * vdata[3 * NV + i0];
    double t1 = b1 * vdata[3 * NV + i1];
    double t2 = b2 * vdata[3 * NV + i2];
    double den = (t0 + t1) + t2;
    if (!(fabs(den) > 1e-8)) den = 1.0;
    cr = (float)((((t0 * (double)vc[i0 * 3 + 0] + t1 * (double)vc[i1 * 3 + 0]) +
                   t2 * (double)vc[i2 * 3 + 0])) / den);
    cg = (float)((((t0 * (double)vc[i0 * 3 + 1] + t1 * (double)vc[i1 * 3 + 1]) +
                   t2 * (double)vc[i2 * 3 + 1])) / den);
    cb = (float)((((t0 * (double)vc[i0 * 3 + 2] + t1 * (double)vc[i1 * 3 + 2]) +
                   t2 * (double)vc[i2 * 3 + 2])) / den);
  }
  out[p * 3 + 0] = cr;
  out[p * 3 + 1] = cg;
  out[p * 3 + 2] = cb;
}

extern "C" void kernel_launch(void* const* d_in, const int* in_sizes, int n_in,
                              void* d_out, int out_size, void* d_ws, size_t ws_size,
                              hipStream_t stream) {
  const float* v = (const float*)d_in[0];
  const float* vc = (const float*)d_in[1];
  const int* fidx = (const int*)d_in[2];
  const float* bg = (const float*)d_in[3];
  const float* camf = (const float*)d_in[4];
  const float* camc = (const float*)d_in[5];
  const float* camt = (const float*)d_in[6];
  const float* camrt = (const float*)d_in[7];
  float* out = (float*)d_out;

  char* ws = (char*)d_ws;
  unsigned long long* keys = (unsigned long long*)ws;   // @0
  double* vdata = (double*)(ws + 131072);
  double* tridata = (double*)(ws + 147456);

  hipMemsetAsync(keys, 0xFF, 16384 * sizeof(unsigned long long), stream);
  render_kernel<<<dim3(32, NGROUP), 256, 0, stream>>>(
      v, fidx, camf, camc, camt, camrt, vdata, tridata, keys);
  color_kernel<<<64, 256, 0, stream>>>(keys, vdata, tridata, fidx, vc, bg, out);
}

// Round 11
// 84.290 us; speedup vs baseline: 1.2614x; 1.0254x over previous
//
#include <hip/hip_runtime.h>
#include <math.h>
#include <stdint.h>

#define NV 512
#define NF 1024
#define TRI_STRIDE 16
#define NGROUP 16
#define CHUNK 64

// ws layout (16B-aligned blocks):
//   slots  : u64 [16][16384]    @ 0        (2097152 B)  per-group best keys
//   vdata  : f64 [4][512]       @ 2097152  (16384 B)    xs, ys, z_ndc, inv_w
//   tridata: f64 [1024*16]      @ 2113536  (131072 B)   exact ref-order data
// total 2244608 B
// NOTE: every slot is written unconditionally every launch -> no init/memset
// needed; harness 0xAA poison is harmless.

// r10 champion scan (verbatim) + slot-write protocol instead of atomicMin:
// removes the memset dispatch and all device atomics. NO per-block fences
// (r8: agent-scope release per block => L2 writeback storm).
__global__ __launch_bounds__(256, 4) void render_kernel(
    const float* __restrict__ v, const int* __restrict__ fidx,
    const float* __restrict__ camf, const float* __restrict__ camc,
    const float* __restrict__ camt, const float* __restrict__ camrt,
    double* __restrict__ vdata, double* __restrict__ tridata,
    unsigned long long* __restrict__ slots)
{
  __shared__ double sM[16];
  __shared__ double sxs[NV], sys_[NV], szn[NV];
  __shared__ int svld[NV];
  __shared__ double2 scc[5][CHUNK];   // bbox-compacted coeffs (dense)
  __shared__ int scidx[CHUNK];
  __shared__ int scnt;
  const int tid = threadIdx.x;
  const int tile = blockIdx.x;        // 32 tiles of 32x16
  const int group = blockIdx.y;
  const int tbase = group * CHUNK;
  const int x0 = (tile & 3) << 5;
  const int y0 = (tile >> 2) << 4;

  {
#pragma clang fp contract(off)
    if (tid == 0) {
      // ---- Rodrigues: scalar part f32 (NEP50 weak promotion), matrices f64 ----
      float r0f = camrt[0], r1f = camrt[1], r2f = camrt[2];
      float th = sqrtf(((r0f * r0f + r1f * r1f) + r2f * r2f) + 1e-12f);
      float k0 = r0f / th, k1 = r1f / th, k2 = r2f / th;
      float sthf = sinf(th);
      float cthf = 1.0f - cosf(th);
      double K[3][3] = {{0.0, -(double)k2, (double)k1},
                        {(double)k2, 0.0, -(double)k0},
                        {-(double)k1, (double)k0, 0.0}};
      double KK[3][3];
      for (int i = 0; i < 3; ++i)
        for (int j = 0; j < 3; ++j)
          KK[i][j] = (K[i][0] * K[0][j] + K[i][1] * K[1][j]) + K[i][2] * K[2][j];
      double R[3][3];
      for (int i = 0; i < 3; ++i)
        for (int j = 0; j < 3; ++j) {
          double e = (i == j) ? 1.0 : 0.0;
          R[i][j] = (e + (double)sthf * K[i][j]) + (double)cthf * KK[i][j];
        }
      double Mr[4][4], Mt[4][4];
      for (int i = 0; i < 4; ++i)
        for (int j = 0; j < 4; ++j) {
          Mr[i][j] = (i == j) ? 1.0 : 0.0;
          Mt[i][j] = (i == j) ? 1.0 : 0.0;
        }
      for (int i = 0; i < 3; ++i)
        for (int j = 0; j < 3; ++j) Mr[i][j] = R[j][i];
      Mt[3][0] = (double)camt[0]; Mt[3][1] = (double)camt[1]; Mt[3][2] = (double)camt[2];
      double view[4][4];
      for (int i = 0; i < 4; ++i)
        for (int j = 0; j < 4; ++j)
          view[i][j] = ((Mr[i][0] * Mt[0][j] + Mr[i][1] * Mt[1][j]) +
                        Mr[i][2] * Mt[2][j]) + Mr[i][3] * Mt[3][j];
      float fcam = 0.5f * (camf[0] + camf[1]);
      float nf = 0.1f / fcam;
      float ccx = camc[0], ccy = camc[1];
      float right = (128.0f - (ccx + 0.5f)) * nf;
      float left = -(ccx + 0.5f) * nf;
      float top = (ccy + 0.5f) * nf;
      float bottom = -((128.0f - ccy) + 0.5f) * nf;
      float m00f = 0.2f / (right - left);
      float m02f = (right + left) / (right - left);
      float m11f = 0.2f / (top - bottom);
      float m12f = (top + bottom) / (top - bottom);
      double P[4][4] = {
          {(double)m00f, 0.0, (double)m02f, 0.0},
          {0.0, (double)m11f, (double)m12f, 0.0},
          {0.0, 0.0, -(10.0 + 0.1) / (10.0 - 0.1),
           -2.0 * 10.0 * 0.1 / (10.0 - 0.1)},
          {0.0, 0.0, -1.0, 0.0}};
      for (int i = 0; i < 4; ++i)
        for (int j = 0; j < 4; ++j)
          sM[i * 4 + j] = ((view[i][0] * P[j][0] + view[i][1] * P[j][1]) +
                           view[i][2] * P[j][2]) + view[i][3] * P[j][3];
    }
    __syncthreads();

    // ---- vertex transform, 2 per thread (expressions identical to r6-r10) ----
    for (int i = tid; i < NV; i += 256) {
      double x = (double)v[i * 3 + 0];
      double y = (double)v[i * 3 + 1];
      double zz = (double)v[i * 3 + 2];
      double c0 = ((x * sM[0] + y * sM[4]) + zz * sM[8]) + sM[12];
      double c1 = ((x * sM[1] + y * sM[5]) + zz * sM[9]) + sM[13];
      double c2 = ((x * sM[2] + y * sM[6]) + zz * sM[10]) + sM[14];
      double c3 = ((x * sM[3] + y * sM[7]) + zz * sM[11]) + sM[15];
      int valid = c3 > 1e-8;
      double wsafe = valid ? c3 : 1.0;
      double n0 = c0 / wsafe, n1 = c1 / wsafe, n2 = c2 / wsafe;
      double xs = (n0 * 0.5 + 0.5) * 128.0;
      double ys = (0.5 - n1 * 0.5) * 128.0;
      double iw = 1.0 / wsafe;
      sxs[i] = xs; sys_[i] = ys; szn[i] = n2; svld[i] = valid;
      if (tile == 0 && group == 0) {
        vdata[0 * NV + i] = xs;
        vdata[1 * NV + i] = ys;
        vdata[2 * NV + i] = n2;
        vdata[3 * NV + i] = iw;
      }
    }
    __syncthreads();

    // ---- this block's 64 tris: coeffs in registers, bbox cull, scatter
    //      straight into compacted LDS ----
    if (tid < CHUNK) {
      const int t = tbase + tid;
      int i0 = fidx[t * 3 + 0], i1 = fidx[t * 3 + 1], i2 = fidx[t * 3 + 2];
      double ax = sxs[i0], ay = sys_[i0];
      double bx = sxs[i1], by = sys_[i1];
      double cx = sxs[i2], cy = sys_[i2];
      double p1 = (bx - ax) * (cy - ay);
      double p2 = (by - ay) * (cx - ax);
      double area = p1 - p2;
      bool ok = (fabs(area) > 1e-8) && svld[i0] && svld[i1] && svld[i2];
      double s = (area > 0.0) ? 1.0 : -1.0;
      double inv_abs = ok ? s / area : 1.0;   // 1/|area|, positive
      double kk0 = szn[i0] * inv_abs, kk1 = szn[i1] * inv_abs, kk2 = szn[i2] * inv_abs;

      if (tile == 0) {
        // exact-path record for the color pass (verified round-2 layout)
        double* td = tridata + t * TRI_STRIDE;
        td[0] = bx;  td[1] = by;  td[2] = cx;  td[3] = cy;  td[4] = ax;  td[5] = ay;
        td[6] = s * (cx - bx);  td[7] = s * (cy - by);
        td[8] = s * (ax - cx);  td[9] = s * (ay - cy);
        td[10] = s * (bx - ax); td[11] = s * (by - ay);
        td[12] = kk0; td[13] = kk1; td[14] = kk2;
        td[15] = inv_abs;
      }

      // affine raster coeffs (r5-r10 verified): w_i = A*px+B*py+C sign-folded;
      // w2 = |area| - w0 - w1; NaN area => never inside
      double e0x = cx - bx, e0y = cy - by;
      double e1x = ax - cx, e1y = ay - cy;
      double e2x = bx - ax, e2y = by - ay;
      double A0 = -s * e0y, B0 = s * e0x, C0 = s * (e0y * bx - e0x * by);
      double A1 = -s * e1y, B1 = s * e1x, C1 = s * (e1y * cx - e1x * cy);
      double A2 = -s * e2y, B2 = s * e2x, C2 = s * (e2y * ax - e2x * ay);
      double Az = (A0 * kk0 + A1 * kk1) + A2 * kk2;
      double Bz = (B0 * kk0 + B1 * kk1) + B2 * kk2;
      double Cz = (C0 * kk0 + C1 * kk1) + C2 * kk2;
      double absarea = ok ? (s * area) : __builtin_nan("");

      float bminx, bminy, bmaxx, bmaxy;
      if (ok) {
        bminx = (float)(fmin(fmin(ax, bx), cx) - 0.01);
        bminy = (float)(fmin(fmin(ay, by), cy) - 0.01);
        bmaxx = (float)(fmax(fmax(ax, bx), cx) + 0.01);
        bmaxy = (float)(fmax(fmax(ay, by), cy) + 0.01);
      } else {
        bminx = 1e30f; bminy = 1e30f; bmaxx = -1e30f; bmaxy = -1e30f;
      }
      const float txmin = (float)x0 + 0.5f, txmax = (float)x0 + 31.5f;
      const float tymin = (float)y0 + 0.5f, tymax = (float)y0 + 15.5f;
      bool hit = !(bminx > txmax || bmaxx < txmin || bminy > tymax || bmaxy < tymin);
      unsigned long long m = __ballot(hit);
      int pos = __popcll(m & ((1ull << tid) - 1ull));
      if (hit) {
        scc[0][pos] = make_double2(A0, B0);
        scc[1][pos] = make_double2(C0, A1);
        scc[2][pos] = make_double2(B1, C1);
        scc[3][pos] = make_double2(Az, Bz);
        scc[4][pos] = make_double2(Cz, absarea);
        scidx[pos] = tid;
      }
      if (tid == 0) scnt = (int)__popcll(m);
    }
  }
  __syncthreads();

  // ---- branch-free scan, 2 pixels per thread (verbatim r10) ----
  const int xa = x0 + (tid & 15);
  const int y = y0 + (tid >> 4);
  const double pxa = (double)xa + 0.5, pxb = (double)(xa + 16) + 0.5;
  const double py = (double)y + 0.5;
  const int cnt = scnt;

  double bestza = INFINITY, bestzb = INFINITY;
  int bestia = -1, bestib = -1;
#pragma unroll 4
  for (int j = 0; j < cnt; ++j) {
    double2 c0 = scc[0][j];   // A0 B0   (broadcast b128 reads)
    double2 c1 = scc[1][j];   // C0 A1
    double2 c2 = scc[2][j];   // B1 C1
    double2 c3 = scc[3][j];   // Az Bz
    double2 c4 = scc[4][j];   // Cz |area|
    int torig = scidx[j];     // leaf load, feeds only the selects
    // pixel A
    double w0a = (c0.x * pxa + c0.y * py) + c1.x;
    double w1a = (c1.y * pxa + c2.x * py) + c2.y;
    double za  = (c3.x * pxa + c3.y * py) + c4.x;
    double w2a = (c4.y - w0a) - w1a;
    bool insa = (w0a >= 0.0) & (w1a >= 0.0) & (w2a >= 0.0) &
                (za >= -1.0) & (za <= 1.0) & (za < bestza);
    bestza = insa ? za : bestza;
    bestia = insa ? (tbase + torig) : bestia;
    // pixel B (independent chain)
    double w0b = (c0.x * pxb + c0.y * py) + c1.x;
    double w1b = (c1.y * pxb + c2.x * py) + c2.y;
    double zb  = (c3.x * pxb + c3.y * py) + c4.x;
    double w2b = (c4.y - w0b) - w1b;
    bool insb = (w0b >= 0.0) & (w1b >= 0.0) & (w2b >= 0.0) &
                (zb >= -1.0) & (zb <= 1.0) & (zb < bestzb);
    bestzb = insb ? zb : bestzb;
    bestib = insb ? (tbase + torig) : bestib;
  }

  // unconditional slot writes (sentinel ~0 when no hit) — no atomics, no init
  unsigned long long keya = ~0ull, keyb = ~0ull;
  if (bestia >= 0) {
    unsigned long long zq = (unsigned long long)((bestza + 1.0) * 4503599627370496.0);
    keya = (zq << 10) | (unsigned long long)bestia;
  }
  if (bestib >= 0) {
    unsigned long long zq = (unsigned long long)((bestzb + 1.0) * 4503599627370496.0);
    keyb = (zq << 10) | (unsigned long long)bestib;
  }
  slots[group * 16384 + y * 128 + xa] = keya;
  slots[group * 16384 + y * 128 + xa + 16] = keyb;
}

__global__ __launch_bounds__(256) void color_kernel(
    const unsigned long long* __restrict__ slots,
    const double* __restrict__ vdata, const double* __restrict__ tridata,
    const int* __restrict__ fidx, const float* __restrict__ vc,
    const float* __restrict__ bg, float* __restrict__ out)
{
  const int p = blockIdx.x * 256 + threadIdx.x;
  if (p >= 16384) return;
  const int x = p & 127, y = p >> 7;

  // reduce 16 group slots (coalesced plane reads); lexicographic min ==
  // the old atomicMin result exactly
  unsigned long long key = ~0ull;
#pragma unroll
  for (int g = 0; g < NGROUP; ++g) {
    unsigned long long k = slots[g * 16384 + p];
    key = (k < key) ? k : key;
  }

  float cr, cg, cb;
  if (key == ~0ull) {
    cr = bg[0]; cg = bg[1]; cb = bg[2];
  } else {
    unsigned int t = (unsigned int)(key & 1023ull);
    const double* td = tridata + t * TRI_STRIDE;
    double px = (double)x + 0.5, py = (double)y + 0.5;
    double w0 = td[6] * (py - td[1]) - td[7] * (px - td[0]);
    double w1 = td[8] * (py - td[3]) - td[9] * (px - td[2]);
    double w2 = td[10] * (py - td[5]) - td[11] * (px - td[4]);
    double inv = td[15];
    double b0 = w0 * inv, b1 = w1 * inv, b2 = w2 * inv;
    int i0 = fidx[t * 3 + 0], i1 = fidx[t * 3 + 1], i2 = fidx[t * 3 + 2];
    double t0 = b0 * vdata[3 * NV + i0];
    double t1 = b1 * vdata[3 * NV + i1];
    double t2 = b2 * vdata[3 * NV + i2];
    double den = (t0 + t1) + t2;
    if (!(fabs(den) > 1e-8)) den = 1.0;
    cr = (float)((((t0 * (double)vc[i0 * 3 + 0] + t1 * (double)vc[i1 * 3 + 0]) +
                   t2 * (double)vc[i2 * 3 + 0])) / den);
    cg = (float)((((t0 * (double)vc[i0 * 3 + 1] + t1 * (double)vc[i1 * 3 + 1]) +
                   t2 * (double)vc[i2 * 3 + 1])) / den);
    cb = (float)((((t0 * (double)vc[i0 * 3 + 2] + t1 * (double)vc[i1 * 3 + 2]) +
                   t2 * (double)vc[i2 * 3 + 2])) / den);
  }
  out[p * 3 + 0] = cr;
  out[p * 3 + 1] = cg;
  out[p * 3 + 2] = cb;
}

extern "C" void kernel_launch(void* const* d_in, const int* in_sizes, int n_in,
                              void* d_out, int out_size, void* d_ws, size_t ws_size,
                              hipStream_t stream) {
  const float* v = (const float*)d_in[0];
  const float* vc = (const float*)d_in[1];
  const int* fidx = (const int*)d_in[2];
  const float* bg = (const float*)d_in[3];
  const float* camf = (const float*)d_in[4];
  const float* camc = (const float*)d_in[5];
  const float* camt = (const float*)d_in[6];
  const float* camrt = (const float*)d_in[7];
  float* out = (float*)d_out;

  char* ws = (char*)d_ws;
  unsigned long long* slots = (unsigned long long*)ws;   // @0, 2 MB
  double* vdata = (double*)(ws + 2097152);
  double* tridata = (double*)(ws + 2113536);

  render_kernel<<<dim3(32, NGROUP), 256, 0, stream>>>(
      v, fidx, camf, camc, camt, camrt, vdata, tridata, slots);
  color_kernel<<<64, 256, 0, stream>>>(slots, vdata, tridata, fidx, vc, bg, out);
}